// Round 20
// baseline (731.252 us; speedup 1.0000x reference)
//
#include <hip/hip_runtime.h>
#include <hip/hip_bf16.h>

// CGCNN forward. R20 = R19 with conv_fused at ONE counted wait + TWO barriers
// per tile: s2 double-buffered (4 x 12KB LDS buffers, 51KB total, still 3
// blocks/CU at 153KB), so issue2(T+2) joins issue0/1(T+1) in one end-of-tile
// clump and every load gets a full tile of flight.
// Pinned per-tile order: [wait][bar][72 MFMA][stores][nbstage ds][lgkm][bar]
// [issue0/1(T+1), issue2(T+2)][idx]. At tile T's wait, newer than s1(T):
// s2 clump (3) + idx (1) -> steady vmcnt(4) (mode-independent; stores are
// OLDER than the waited loads); !have3 -> 3; last tile -> 0.
// Math identical to R19 -> absmax unchanged.

#define NN    100000
#define MM    12
#define ORIG  92
#define FF    64
#define NBR   41
#define HH    128
#define NCONV 3
#define CC    3125
#define K2    169
#define GG    128
#define EPSV  1e-5f

#define TILE_ATOMS 8
#define TILE_ROWS  96                  // 8 atoms * 12 edges
#define NTILES     (NN / TILE_ATOMS)   // 12500
#define SLOTS      24                  // full-K slots per A row (fallback kernel)
#define WPK_L      (48 * 64 * 8)       // ushorts per layer of packed W
#define CONV_GRID  750                 // <= 768 resident at 3 blk/CU
#define ETILES     1563                // ceil(NN/64)
#define PCHUNK_ROWS 128
#define PCHUNK_F32  (PCHUNK_ROWS * NBR)        // 5248 f32 = 20992 B (16B aligned)
#define PCHUNK_U4   (PCHUNK_F32 / 4)           // 1312
#define NPCHUNK     ((NN * MM) / PCHUNK_ROWS)  // 9375
#define LOG2E_F    1.44269504088896341f
#define LN2_F      0.69314718055994531f

typedef __attribute__((ext_vector_type(8))) short bf16x8;
typedef __attribute__((ext_vector_type(4))) float f32x4;

__device__ __forceinline__ float softplusf(float v) {
    return fmaxf(v, 0.f) + log1pf(expf(-fabsf(v)));
}
__device__ __forceinline__ float sigmoidf_(float v) {
    return 1.f / (1.f + expf(-v));
}
__device__ __forceinline__ ushort f2bf(float f) {
    __hip_bfloat16 h = __float2bfloat16(f);
    return *(ushort*)&h;
}
__device__ __forceinline__ float bf2f(ushort h) {
    uint u = ((uint)h) << 16;
    return __uint_as_float(u);
}
// async global->LDS, 16B per lane; LDS dest = wave-uniform base + lane*16
__device__ __forceinline__ void gload_lds16(const void* gsrc, void* ldst) {
    __builtin_amdgcn_global_load_lds(
        (const __attribute__((address_space(1))) unsigned int*)gsrc,
        (__attribute__((address_space(3))) unsigned int*)ldst, 16, 0, 0);
}

// ---------------- packWemb ----------------
__global__ void packWemb_kernel(const float* __restrict__ embW, const float* __restrict__ mask,
                                ushort* __restrict__ wemb) {
    int b = blockIdx.x;            // 0..11 = cf*3 + kk
    int cf = b / 3;
    int kk = b - cf * 3;
    int lane = threadIdx.x;
    int c = cf * 16 + (lane & 15);
#pragma unroll
    for (int i = 0; i < 8; i++) {
        int k = kk * 32 + (lane >> 4) * 8 + i;
        float v = (k < ORIG) ? mask[k] * embW[k * FF + c] : 0.f;
        wemb[((size_t)b * 64 + lane) * 8 + i] = f2bf(v);
    }
}

// ---------------- embed_mfma ----------------
__launch_bounds__(256)
__global__ void embed_mfma(const float* __restrict__ af, const ushort* __restrict__ wemb,
                           const float* __restrict__ embb,
                           float* __restrict__ x, ushort* __restrict__ xb) {
    __shared__ __align__(16) ushort Ae[64 * 128];
    const int t = threadIdx.x;
    const int lane = t & 63;
    const int w = t >> 6;
    const int l15 = lane & 15;
    const int lg = lane >> 4;
    const int a0 = blockIdx.x * 64;

    bf16x8 bfrag[4][3];
#pragma unroll
    for (int cf = 0; cf < 4; cf++)
#pragma unroll
        for (int kk = 0; kk < 3; kk++)
            bfrag[cf][kk] = *(const bf16x8*)&wemb[(((size_t)(cf * 3 + kk)) * 64 + lane) * 8];

#pragma unroll
    for (int uu = 0; uu < 3; uu++) {
        int u = uu * 256 + t;
        int row = u / 12;
        int slot = u - row * 12;
        int a = a0 + row;
        if (a >= NN) a = NN - 1;
        const float* src = af + (size_t)a * ORIG + slot * 8;
        float v[8];
        float4 p0 = *(const float4*)src;
        v[0] = p0.x; v[1] = p0.y; v[2] = p0.z; v[3] = p0.w;
        if (slot < 11) {
            float4 p1 = *(const float4*)(src + 4);
            v[4] = p1.x; v[5] = p1.y; v[6] = p1.z; v[7] = p1.w;
        } else {
            v[4] = v[5] = v[6] = v[7] = 0.f;
        }
        uint4 val;
        val.x = (uint)f2bf(v[0]) | ((uint)f2bf(v[1]) << 16);
        val.y = (uint)f2bf(v[2]) | ((uint)f2bf(v[3]) << 16);
        val.z = (uint)f2bf(v[4]) | ((uint)f2bf(v[5]) << 16);
        val.w = (uint)f2bf(v[6]) | ((uint)f2bf(v[7]) << 16);
        *(uint4*)&Ae[row * 128 + ((slot ^ (row & 7)) * 8)] = val;
    }
    __syncthreads();

    f32x4 acc[4];
#pragma unroll
    for (int cf = 0; cf < 4; cf++) acc[cf] = (f32x4){0.f, 0.f, 0.f, 0.f};

#pragma unroll
    for (int kk = 0; kk < 3; kk++) {
        int row = w * 16 + l15;
        int slot = kk * 4 + lg;
        bf16x8 a = *(const bf16x8*)&Ae[row * 128 + ((slot ^ (row & 7)) * 8)];
#pragma unroll
        for (int cf = 0; cf < 4; cf++)
            acc[cf] = __builtin_amdgcn_mfma_f32_16x16x32_bf16(a, bfrag[cf][kk], acc[cf], 0, 0, 0);
    }

#pragma unroll
    for (int cf = 0; cf < 4; cf++) {
        int c = cf * 16 + l15;
        float bb = embb[c];
#pragma unroll
        for (int q = 0; q < 4; q++) {
            int a = a0 + w * 16 + lg * 4 + q;
            if (a < NN) {
                float v = acc[cf][q] + bb;
                x[(size_t)a * FF + c] = v;
                xb[(size_t)a * FF + c] = f2bf(v);
            }
        }
    }
}

// ---------------- packW ----------------
__global__ void packW_kernel(const float* __restrict__ fcW, ushort* __restrict__ wpk) {
    int b = blockIdx.x;            // 0..143 = l*48 + cf*6 + kk
    int l = b / 48;
    int r = b - l * 48;
    int cf = r / 6;
    int kk = r - cf * 6;
    int lane = threadIdx.x;
    int c = cf * 16 + (lane & 15);
#pragma unroll
    for (int i = 0; i < 8; i++) {
        int k = kk * 32 + (lane >> 4) * 8 + i;
        float v = (k < K2) ? fcW[(l * K2 + k) * GG + c] : 0.f;
        wpk[((size_t)b * 64 + lane) * 8 + i] = f2bf(v);
    }
}

// ---------------- prepack_nbr v2: LDS-staged coalesced conversion ----------------
__launch_bounds__(256)
__global__ void prepack_nbr(const float* __restrict__ nbr_fea, ushort* __restrict__ nbrb) {
    __shared__ float buf[PCHUNK_F32];   // 20.5 KB
    const int t = threadIdx.x;
    for (int chunk = blockIdx.x; chunk < NPCHUNK; chunk += gridDim.x) {
        const uint4* src = (const uint4*)(nbr_fea + (size_t)chunk * PCHUNK_F32);
        __syncthreads();   // protect buf from previous iteration readers
#pragma unroll
        for (int i = 0; i < 6; i++) {
            int u = i * 256 + t;
            if (u < PCHUNK_U4) *(uint4*)&buf[u * 4] = src[u];
        }
        __syncthreads();
#pragma unroll
        for (int i = 0; i < 4; i++) {   // 1024 out units = 4*256
            int u = i * 256 + t;
            int row = u >> 3;
            int kb = (u & 7) * 8;
            ushort h[8];
#pragma unroll
            for (int j = 0; j < 8; j++)
                h[j] = (kb + j < NBR) ? f2bf(buf[row * NBR + kb + j]) : (ushort)0;
            uint4 val;
            val.x = (uint)h[0] | ((uint)h[1] << 16);
            val.y = (uint)h[2] | ((uint)h[3] << 16);
            val.z = (uint)h[4] | ((uint)h[5] << 16);
            val.w = (uint)h[6] | ((uint)h[7] << 16);
            *(uint4*)&nbrb[((size_t)chunk * PCHUNK_ROWS + row) * 64 + kb] = val;
        }
    }
}

// ---------------- conv_fused: single-wait 4-buffer pipeline, (256,3) ----------------
// Buffers: As[0]=s0, As[1]=s1 (single-buffered), As[2+p]=s2 double-buffered.
template <int MODE>
__launch_bounds__(256, 3)
__global__ void conv_fused(const ushort* __restrict__ xb, const ushort* __restrict__ nbrb,
                           const int* __restrict__ nidx, const ushort* __restrict__ wpk_l,
                           const float* __restrict__ fcb_l,
                           float* __restrict__ stats,
                           const float* __restrict__ sc1, const float* __restrict__ sh1,
                           float* __restrict__ summed, float* __restrict__ stats2) {
    __shared__ __align__(16) ushort As[4][TILE_ROWS * 64];   // 4 x 12 KB
    __shared__ int nbstage[2][TILE_ROWS];
    __shared__ float red[256];

    const int t = threadIdx.x;
    const int lane = t & 63;
    const int w = t >> 6;
    const int l15 = lane & 15;
    const int lg = lane >> 4;

    bf16x8 bfrag[2][6];
#pragma unroll
    for (int c2 = 0; c2 < 2; c2++)
#pragma unroll
        for (int kk = 0; kk < 6; kk++)
            bfrag[c2][kk] = *(const bf16x8*)&wpk_l[((((w + 4 * c2) * 6 + kk) * 64 + lane) * 8)];

    const int chF = w * 16 + l15;
    float scF = 0.f, shF = 0.f, scC = 0.f, shC = 0.f;
    if (MODE == 1) {
        scF = sc1[chF]; shF = sh1[chF];
        scC = sc1[chF + 64]; shC = sh1[chF + 64];
    }

    float sAF = 0.f, sBF = 0.f, sAC = 0.f, sBC = 0.f;
    float s2a = 0.f, s2b = 0.f;

    int pt = t; if (pt >= TILE_ROWS) pt -= TILE_ROWS; if (pt >= TILE_ROWS) pt -= TILE_ROWS;
    const int pidx = (pt & 7) * MM + (pt >> 3);

    int rowi[3], sli[3];
#pragma unroll
    for (int i = 0; i < 3; i++) {
        int u = w * 192 + i * 64 + lane;
        rowi[i] = u >> 3;
        sli[i] = (u & 7) ^ (rowi[i] & 7);
    }
    const ushort* p0p[3];
    const ushort* p2p[3];
#pragma unroll
    for (int i = 0; i < 3; i++) {
        p0p[i] = xb + ((size_t)blockIdx.x * TILE_ATOMS + (rowi[i] & 7)) * 64 + sli[i] * 8;
        p2p[i] = nbrb + ((size_t)blockIdx.x * TILE_ROWS + (rowi[i] & 7) * MM + (rowi[i] >> 3)) * 64
                 + sli[i] * 8;
    }
    const size_t st0 = (size_t)CONV_GRID * TILE_ATOMS * 64;
    const size_t st2 = (size_t)CONV_GRID * TILE_ROWS * 64;

    auto issue0 = [&]() {
#pragma unroll
        for (int i = 0; i < 3; i++) {
            gload_lds16(p0p[i], &As[0][(w * 192 + i * 64) * 8]);
            p0p[i] += st0;
        }
    };
    auto issue1 = [&](int nb) {
#pragma unroll
        for (int i = 0; i < 3; i++)
            gload_lds16(xb + (size_t)nbstage[nb][rowi[i]] * 64 + sli[i] * 8,
                        &As[1][(w * 192 + i * 64) * 8]);
    };
    auto issue2 = [&](int pb) {   // s2 -> As[2+pb]; advances p2p one tile
#pragma unroll
        for (int i = 0; i < 3; i++) {
            gload_lds16(p2p[i], &As[2 + pb][(w * 192 + i * 64) * 8]);
            p2p[i] += st2;
        }
    };

    int tile = blockIdx.x;   // grid 750, NTILES 12500: every block has >= 16 tiles
    int idx_cur;
    {   // prologue: nbstage T0/T1; idx_cur = T2; issue s0/s1(T0), s2(T0), s2(T1)
        int nx0 = nidx[tile * TILE_ROWS + pidx];
        int nx1 = nidx[(tile + CONV_GRID) * TILE_ROWS + pidx];
        if (t < TILE_ROWS) { nbstage[0][t] = nx0; nbstage[1][t] = nx1; }
        __syncthreads();
        idx_cur = nidx[(tile + 2 * CONV_GRID) * TILE_ROWS + pidx];
        issue0(); issue1(0); issue2(0);
        if (tile + CONV_GRID < NTILES) issue2(1);
        asm volatile("" ::: "memory");
    }

    for (int it = 0; tile < NTILES; tile += CONV_GRID, ++it) {
        const bool have1 = (tile + CONV_GRID)     < NTILES;
        const bool have2 = (tile + 2 * CONV_GRID) < NTILES;
        const bool have3 = (tile + 3 * CONV_GRID) < NTILES;
        const int pb = it & 1;

        int idx_next = 0;
        if (have3) idx_next = nidx[(tile + 3 * CONV_GRID) * TILE_ROWS + pidx];

        // ---- single counted wait: all of s0(T), s1(T), s2(T) complete ----
        if (!have1)     { asm volatile("s_waitcnt vmcnt(0)" ::: "memory"); }
        else if (have3) { asm volatile("s_waitcnt vmcnt(4)" ::: "memory"); }
        else            { asm volatile("s_waitcnt vmcnt(3)" ::: "memory"); }
        __builtin_amdgcn_s_barrier();
        __builtin_amdgcn_sched_barrier(0);

        f32x4 acc[6][2];
#pragma unroll
        for (int rf = 0; rf < 6; rf++)
#pragma unroll
            for (int c2 = 0; c2 < 2; c2++) acc[rf][c2] = (f32x4){0.f, 0.f, 0.f, 0.f};

        // ---- 72 MFMA: s0 (kk 0,1), s1 (kk 2,3), s2 (kk 4,5) ----
#pragma unroll
        for (int sb = 0; sb < 3; sb++) {
            const ushort* Ab = (sb < 2) ? As[sb] : As[2 + pb];
#pragma unroll
            for (int kx = 0; kx < 2; kx++) {
                int kk = sb * 2 + kx;
#pragma unroll
                for (int rf = 0; rf < 6; rf++) {
                    int row = rf * 16 + l15;
                    int s8r = kx * 4 + lg;
                    bf16x8 a = *(const bf16x8*)&Ab[row * 64 + ((s8r ^ (row & 7)) * 8)];
                    acc[rf][0] = __builtin_amdgcn_mfma_f32_16x16x32_bf16(a, bfrag[0][kk], acc[rf][0], 0, 0, 0);
                    acc[rf][1] = __builtin_amdgcn_mfma_f32_16x16x32_bf16(a, bfrag[1][kk], acc[rf][1], 0, 0, 0);
                }
            }
        }

        // ---- epilogue ----
        if (MODE == 0) {
#pragma unroll
            for (int rf = 0; rf < 6; rf++)
#pragma unroll
                for (int q = 0; q < 4; q++) {
                    float a0 = acc[rf][0][q];
                    float a1 = acc[rf][1][q];
                    sAF += a0; sBF = fmaf(a0, a0, sBF);
                    sAC += a1; sBC = fmaf(a1, a1, sBC);
                }
        } else {
            float psum[4] = {0.f, 0.f, 0.f, 0.f};
#pragma unroll
            for (int rf = 0; rf < 6; rf++)
#pragma unroll
                for (int q = 0; q < 4; q++) {
                    float gF = fmaf(acc[rf][0][q], scF, shF);   // log2 domain
                    float gC = fmaf(acc[rf][1][q], scC, shC);
                    float sig = __builtin_amdgcn_rcpf(1.f + __builtin_amdgcn_exp2f(-gF));
                    float sp  = fmaxf(gC, 0.f)
                              + __builtin_amdgcn_logf(1.f + __builtin_amdgcn_exp2f(-fabsf(gC)));
                    psum[q] = fmaf(sig, sp, psum[q]);
                }
#pragma unroll
            for (int q = 0; q < 4; q++) {
                psum[q] *= LN2_F;
                psum[q] += __shfl_xor(psum[q], 32, 64);
            }
            if (lg < 2) {
                int atom0 = tile * TILE_ATOMS;
#pragma unroll
                for (int q = 0; q < 4; q++) {
                    int a_loc = (lg & 1) * 4 + q;
                    float sm = psum[q];
                    summed[(size_t)(atom0 + a_loc) * FF + chF] = sm;
                    s2a += sm; s2b += sm * sm;
                }
            }
        }

        // nbstage <- idx_cur (for T+2; loaded >=1 tile ago, implicit wait loose)
        if (have2 && t < TILE_ROWS) nbstage[it & 1][t] = idx_cur;
        idx_cur = idx_next;
        asm volatile("s_waitcnt lgkmcnt(0)" ::: "memory");
        __builtin_amdgcn_s_barrier();   // all reads of As + nbstage done

        // ---- end-of-tile issue clump: s0/s1(T+1), s2(T+2) ----
        if (have1) {
            issue0();
            issue1((it + 1) & 1);
            if (have2) issue2(pb);   // consumed at T+2 with same parity
        }
        asm volatile("" ::: "memory");
    }

    // ------- end-of-kernel stats reductions -------
    if (MODE == 0) {
        __syncthreads(); red[t] = sAF; __syncthreads();
        if (t < 64) {
            float s = 0.f;
#pragma unroll
            for (int g2 = 0; g2 < 4; g2++) s += red[(t >> 4) * 64 + g2 * 16 + (t & 15)];
            atomicAdd(&stats[t], s);
        }
        __syncthreads(); red[t] = sBF; __syncthreads();
        if (t < 64) {
            float s = 0.f;
#pragma unroll
            for (int g2 = 0; g2 < 4; g2++) s += red[(t >> 4) * 64 + g2 * 16 + (t & 15)];
            atomicAdd(&stats[128 + t], s);
        }
        __syncthreads(); red[t] = sAC; __syncthreads();
        if (t < 64) {
            float s = 0.f;
#pragma unroll
            for (int g2 = 0; g2 < 4; g2++) s += red[(t >> 4) * 64 + g2 * 16 + (t & 15)];
            atomicAdd(&stats[64 + t], s);
        }
        __syncthreads(); red[t] = sBC; __syncthreads();
        if (t < 64) {
            float s = 0.f;
#pragma unroll
            for (int g2 = 0; g2 < 4; g2++) s += red[(t >> 4) * 64 + g2 * 16 + (t & 15)];
            atomicAdd(&stats[192 + t], s);
        }
    } else {
        __syncthreads(); red[t] = s2a; __syncthreads();
        if (t < 64) {
            float s = 0.f;
#pragma unroll
            for (int g2 = 0; g2 < 4; g2++) s += red[(t >> 4) * 64 + g2 * 16 + (t & 15)];
            atomicAdd(&stats2[t], s);
        }
        __syncthreads(); red[t] = s2b; __syncthreads();
        if (t < 64) {
            float s = 0.f;
#pragma unroll
            for (int g2 = 0; g2 < 4; g2++) s += red[(t >> 4) * 64 + g2 * 16 + (t & 15)];
            atomicAdd(&stats2[64 + t], s);
        }
    }
}

// ---------------- legacy R4 two-pass conv (ws fallback; raw-acc stats, fold=0) ----------------
template <int PASS>
__launch_bounds__(256, 2)
__global__ void conv_mfma(const ushort* __restrict__ xb, const float* __restrict__ nbr_fea,
                          const int* __restrict__ nidx, const ushort* __restrict__ wpk_l,
                          const float* __restrict__ fcb_l,
                          float* __restrict__ stats,
                          const float* __restrict__ sc1, const float* __restrict__ sh1,
                          float* __restrict__ summed, float* __restrict__ stats2) {
    __shared__ __align__(16) ushort As[TILE_ROWS * 192];
    __shared__ int nb[TILE_ROWS];
    __shared__ float gacc[TILE_ATOMS * FF];
    __shared__ float red[256];

    const int t = threadIdx.x;
    const int lane = t & 63;
    const int w = t >> 6;
    const int l15 = lane & 15;
    const int lg = lane >> 4;

    bf16x8 bfrag[2][6];
#pragma unroll
    for (int c2 = 0; c2 < 2; c2++)
#pragma unroll
        for (int kk = 0; kk < 6; kk++)
            bfrag[c2][kk] = *(const bf16x8*)&wpk_l[((((w + 4 * c2) * 6 + kk) * 64 + lane) * 8)];

    const int chF = w * 16 + l15;
    const int chC = chF + 64;
    const float bF = fcb_l[chF], bC = fcb_l[chC];
    float scF = 0.f, shF = 0.f, scC = 0.f, shC = 0.f;
    if (PASS == 1) { scF = sc1[chF]; shF = sh1[chF]; scC = sc1[chC]; shC = sh1[chC]; }

    float sAF = 0.f, sBF = 0.f, sAC = 0.f, sBC = 0.f;
    float s2a = 0.f, s2b = 0.f;

    for (int tile = blockIdx.x; tile < NTILES; tile += gridDim.x) {
        const int ebase = tile * TILE_ROWS;
        __syncthreads();
        if (t < TILE_ROWS) nb[t] = nidx[ebase + t];
        if (PASS == 1) { gacc[t] = 0.f; gacc[256 + t] = 0.f; }
        __syncthreads();

#pragma unroll
        for (int e = t; e < TILE_ROWS * SLOTS; e += 256) {
            int row = e / SLOTS;
            int slot = e - row * SLOTS;
            uint4 val;
            if (slot < 16) {
                int a = (slot < 8) ? (tile * TILE_ATOMS + row / 12) : nb[row];
                val = *(const uint4*)&xb[a * 64 + (slot & 7) * 8];
            } else {
                int kb = (slot - 16) * 8;
                const float* src = nbr_fea + (size_t)(ebase + row) * NBR + kb;
                ushort h[8];
#pragma unroll
                for (int i = 0; i < 8; i++)
                    h[i] = (kb + i < NBR) ? f2bf(src[i]) : (ushort)0;
                val.x = (uint)h[0] | ((uint)h[1] << 16);
                val.y = (uint)h[2] | ((uint)h[3] << 16);
                val.z = (uint)h[4] | ((uint)h[5] << 16);
                val.w = (uint)h[6] | ((uint)h[7] << 16);
            }
            *(uint4*)&As[row * 192 + ((slot ^ (row & 7)) * 8)] = val;
        }
        __syncthreads();

        f32x4 acc[6][2];
#pragma unroll
        for (int rf = 0; rf < 6; rf++)
#pragma unroll
            for (int c2 = 0; c2 < 2; c2++) acc[rf][c2] = (f32x4){0.f, 0.f, 0.f, 0.f};

#pragma unroll
        for (int kk = 0; kk < 6; kk++) {
#pragma unroll
            for (int rf = 0; rf < 6; rf++) {
                int row = rf * 16 + l15;
                int slot = kk * 4 + lg;
                bf16x8 a = *(const bf16x8*)&As[row * 192 + ((slot ^ (row & 7)) * 8)];
                acc[rf][0] = __builtin_amdgcn_mfma_f32_16x16x32_bf16(a, bfrag[0][kk], acc[rf][0], 0, 0, 0);
                acc[rf][1] = __builtin_amdgcn_mfma_f32_16x16x32_bf16(a, bfrag[1][kk], acc[rf][1], 0, 0, 0);
            }
        }

        if (PASS == 0) {
#pragma unroll
            for (int rf = 0; rf < 6; rf++)
#pragma unroll
                for (int q = 0; q < 4; q++) {
                    float a0 = acc[rf][0][q];
                    float a1 = acc[rf][1][q];
                    sAF += a0; sBF = fmaf(a0, a0, sBF);
                    sAC += a1; sBC = fmaf(a1, a1, sBC);
                }
        } else {
#pragma unroll
            for (int rf = 0; rf < 6; rf++) {
                int r0 = rf * 16 + lg * 4;
                float p = 0.f;
#pragma unroll
                for (int q = 0; q < 4; q++) {
                    float gF = (acc[rf][0][q] + bF) * scF + shF;
                    float gC = (acc[rf][1][q] + bC) * scC + shC;
                    p += sigmoidf_(gF) * softplusf(gC);
                }
                atomicAdd(&gacc[(r0 / 12) * FF + chF], p);
            }
            __syncthreads();
#pragma unroll
            for (int rep = 0; rep < 2; rep++) {
                int idx = rep * 256 + t;
                int a = idx >> 6, c = idx & 63;
                float sm = gacc[idx];
                summed[(tile * TILE_ATOMS + a) * FF + c] = sm;
                s2a += sm; s2b += sm * sm;
            }
        }
    }

    if (PASS == 0) {
        __syncthreads(); red[t] = sAF; __syncthreads();
        if (t < 64) {
            float s = 0.f;
#pragma unroll
            for (int g2 = 0; g2 < 4; g2++) s += red[(t >> 4) * 64 + g2 * 16 + (t & 15)];
            atomicAdd(&stats[t], s);
        }
        __syncthreads(); red[t] = sBF; __syncthreads();
        if (t < 64) {
            float s = 0.f;
#pragma unroll
            for (int g2 = 0; g2 < 4; g2++) s += red[(t >> 4) * 64 + g2 * 16 + (t & 15)];
            atomicAdd(&stats[128 + t], s);
        }
        __syncthreads(); red[t] = sAC; __syncthreads();
        if (t < 64) {
            float s = 0.f;
#pragma unroll
            for (int g2 = 0; g2 < 4; g2++) s += red[(t >> 4) * 64 + g2 * 16 + (t & 15)];
            atomicAdd(&stats[64 + t], s);
        }
        __syncthreads(); red[t] = sBC; __syncthreads();
        if (t < 64) {
            float s = 0.f;
#pragma unroll
            for (int g2 = 0; g2 < 4; g2++) s += red[(t >> 4) * 64 + g2 * 16 + (t & 15)];
            atomicAdd(&stats[192 + t], s);
        }
    } else {
        __syncthreads(); red[t] = s2a; __syncthreads();
        if (t < 64) {
            float s = red[t] + red[64 + t] + red[128 + t] + red[192 + t];
            atomicAdd(&stats2[t], s);
        }
        __syncthreads(); red[t] = s2b; __syncthreads();
        if (t < 64) {
            float s = red[t] + red[64 + t] + red[128 + t] + red[192 + t];
            atomicAdd(&stats2[64 + t], s);
        }
    }
}

// ---------------- bn finalize ----------------
__global__ void fin1_kernel(const float* __restrict__ stats, const float* __restrict__ fcb_l,
                            const float* __restrict__ g, const float* __restrict__ b,
                            float* __restrict__ sc, float* __restrict__ sh, int fold) {
    int c = threadIdx.x;  // 128
    const float inv = 1.f / (float)(NN * MM);
    float bia = fcb_l[c];
    float Sa = stats[c], Sb = stats[128 + c];
    float mu = Sa * inv + bia;
    float ex2 = (Sb + 2.f * bia * Sa) * inv + bia * bia;
    float var = ex2 - mu * mu;
    float s = rsqrtf(var + EPSV) * g[c];
    float scv = s;
    float shv = b[c] - mu * s;
    if (fold) { scv *= LOG2E_F; shv *= LOG2E_F; }
    sc[c] = scv;
    sh[c] = shv;
}

__global__ void fin2_kernel(const float* __restrict__ stats2, const float* __restrict__ g,
                            const float* __restrict__ b, float* __restrict__ sc, float* __restrict__ sh) {
    int c = threadIdx.x;  // 64
    const float inv = 1.f / (float)NN;
    float mu = stats2[c] * inv;
    float var = stats2[64 + c] * inv - mu * mu;
    float s = rsqrtf(var + EPSV) * g[c];
    sc[c] = s;
    sh[c] = b[c] - mu * s;
}

// ---------------- x = softplus(x + bn2(summed)) ; refresh xb ----------------
__global__ void update_x_kernel(float* __restrict__ x, ushort* __restrict__ xb,
                                const float* __restrict__ summed,
                                const float* __restrict__ sc2, const float* __restrict__ sh2) {
    for (int idx = blockIdx.x * blockDim.x + threadIdx.x; idx < NN * FF;
         idx += gridDim.x * blockDim.x) {
        int c = idx & 63;
        float v = softplusf(x[idx] + summed[idx] * sc2[c] + sh2[c]);
        x[idx] = v;
        xb[idx] = f2bf(v);
    }
}

// ---------------- last layer: update_x fused with segment pooling ----------------
__global__ void update_x_pool_kernel(const float* __restrict__ x,
                                     const float* __restrict__ summed,
                                     const float* __restrict__ sc2, const float* __restrict__ sh2,
                                     const int* __restrict__ seg,
                                     float* __restrict__ csum, float* __restrict__ ccnt) {
    for (int idx = blockIdx.x * blockDim.x + threadIdx.x; idx < NN * FF;
         idx += gridDim.x * blockDim.x) {
        int i = idx >> 6;
        int c = idx & 63;
        float v = softplusf(x[idx] + summed[idx] * sc2[c] + sh2[c]);
        atomicAdd(&csum[seg[i] * FF + c], v);
        if (c == 0) atomicAdd(&ccnt[seg[i]], 1.f);
    }
}

// ---------------- per-crystal head ----------------
__global__ void head_kernel(const float* __restrict__ csum, const float* __restrict__ ccnt,
                            const float* __restrict__ c2fW, const float* __restrict__ c2fb,
                            const float* __restrict__ outW, const float* __restrict__ outb,
                            float* __restrict__ out) {
    __shared__ float pl[FF];
    __shared__ float red[HH];
    int c = blockIdx.x;
    int t = threadIdx.x;
    if (t < FF) {
        float cnt = fmaxf(ccnt[c], 1.f);
        pl[t] = softplusf(csum[c * FF + t] / cnt);
    }
    __syncthreads();
    float acc = c2fb[t];
    for (int f = 0; f < FF; f++) acc += pl[f] * c2fW[f * HH + t];
    red[t] = softplusf(acc) * outW[t];
    __syncthreads();
    for (int s = 64; s > 0; s >>= 1) {
        if (t < s) red[t] += red[t + s];
        __syncthreads();
    }
    if (t == 0) out[c] = red[0] + outb[0];
}

extern "C" void kernel_launch(void* const* d_in, const int* in_sizes, int n_in,
                              void* d_out, int out_size, void* d_ws, size_t ws_size,
                              hipStream_t stream) {
    const float* atom_fea = (const float*)d_in[0];
    const float* nbr_fea  = (const float*)d_in[1];
    const int*   nbr_idx  = (const int*)d_in[2];
    const int*   seg      = (const int*)d_in[3];
    const float* mask = (const float*)d_in[5];
    const float* embW = (const float*)d_in[6];
    const float* embb = (const float*)d_in[7];
    const float* fcW  = (const float*)d_in[8];
    const float* fcb  = (const float*)d_in[9];
    const float* bn1g = (const float*)d_in[10];
    const float* bn1b = (const float*)d_in[11];
    const float* bn2g = (const float*)d_in[12];
    const float* bn2b = (const float*)d_in[13];
    const float* c2fW = (const float*)d_in[14];
    const float* c2fb = (const float*)d_in[15];
    const float* outW = (const float*)d_in[16];
    const float* outb = (const float*)d_in[17];
    float* out = (float*)d_out;

    // ws layout (f32 region, then ushort region; ccnt adjacent to csum!)
    float* ws     = (float*)d_ws;
    float* x      = ws;                       // N*F
    float* summed = x + NN * FF;              // N*F
    float* csum   = summed + NN * FF;         // CC*FF
    float* ccnt   = csum + CC * FF;           // CC (+3 pad -> 3128)
    float* stats  = ccnt + 3128;              // 256
    float* stats2 = stats + 256;              // 128
    float* sc1    = stats2 + 128;             // 128
    float* sh1    = sc1 + 128;                // 128
    float* sc2    = sh1 + 128;                // 64
    float* sh2    = sc2 + 64;                 // 64
    ushort* xb    = (ushort*)(sh2 + 64);      // N*F bf16
    ushort* wpk   = xb + NN * FF;             // 3 * WPK_L
    ushort* wemb  = wpk + 3 * WPK_L;          // 6144 (pad 8192)
    ushort* nbrb  = wemb + 8192;              // N*M*64 bf16

    const size_t need_full =
        (size_t)((char*)(nbrb + (size_t)NN * MM * 64) - (char*)d_ws);
    const bool full = (ws_size >= need_full);

    packW_kernel<<<144, 64, 0, stream>>>(fcW, wpk);
    packWemb_kernel<<<12, 64, 0, stream>>>(embW, mask, wemb);
    embed_mfma<<<ETILES, 256, 0, stream>>>(atom_fea, wemb, embb, x, xb);
    if (full) prepack_nbr<<<2048, 256, 0, stream>>>(nbr_fea, nbrb);
    hipMemsetAsync(csum, 0, (CC * FF + CC) * sizeof(float), stream);

    for (int l = 0; l < NCONV; l++) {
        const ushort* wpk_l = wpk + l * WPK_L;
        hipMemsetAsync(stats, 0, (256 + 128) * sizeof(float), stream);
        if (full) {
            conv_fused<0><<<CONV_GRID, 256, 0, stream>>>(xb, nbrb, nbr_idx, wpk_l,
                                                         fcb + l * GG, stats,
                                                         nullptr, nullptr, nullptr, nullptr);
            fin1_kernel<<<1, 128, 0, stream>>>(stats, fcb + l * GG,
                                               bn1g + l * GG, bn1b + l * GG, sc1, sh1, 1);
            conv_fused<1><<<CONV_GRID, 256, 0, stream>>>(xb, nbrb, nbr_idx, wpk_l,
                                                         fcb + l * GG, nullptr,
                                                         sc1, sh1, summed, stats2);
        } else {
            conv_mfma<0><<<2048, 256, 0, stream>>>(xb, nbr_fea, nbr_idx, wpk_l, fcb + l * GG,
                                                   stats, nullptr, nullptr, nullptr, nullptr);
            fin1_kernel<<<1, 128, 0, stream>>>(stats, fcb + l * GG,
                                               bn1g + l * GG, bn1b + l * GG, sc1, sh1, 0);
            conv_mfma<1><<<2048, 256, 0, stream>>>(xb, nbr_fea, nbr_idx, wpk_l, fcb + l * GG,
                                                   nullptr, sc1, sh1, summed, stats2);
        }
        fin2_kernel<<<1, 64, 0, stream>>>(stats2, bn2g + l * FF, bn2b + l * FF, sc2, sh2);
        if (l < NCONV - 1) {
            update_x_kernel<<<2048, 256, 0, stream>>>(x, xb, summed, sc2, sh2);
        } else {
            update_x_pool_kernel<<<2048, 256, 0, stream>>>(x, summed, sc2, sh2,
                                                           seg, csum, ccnt);
        }
    }

    head_kernel<<<CC, 128, 0, stream>>>(csum, ccnt, c2fW, c2fb, outW, outb, out);
}

// Round 21
// 715.305 us; speedup vs baseline: 1.0223x; 1.0223x over previous
//
#include <hip/hip_runtime.h>
#include <hip/hip_bf16.h>

// CGCNN forward. R21 = R19 restored (best: 716us; R20's single-wait 4-buffer
// variant was neutral-to-negative). Final configuration:
//   - embed via MFMA (packWemb folds mask into embW)
//   - prepack_nbr v2: LDS-staged coalesced f32->bf16 conversion
//   - conv_fused: K-split sub-tile triple-buffer, merged phase 0+1, register
//     index pipeline (no vmcnt drain), counted vmcnt, (256,3), grid 750
//   - log2-domain gate, raw-acc bn1 stats folded in fin1
//   - last-layer update_x fused with segment pooling; per-crystal head.

#define NN    100000
#define MM    12
#define ORIG  92
#define FF    64
#define NBR   41
#define HH    128
#define NCONV 3
#define CC    3125
#define K2    169
#define GG    128
#define EPSV  1e-5f

#define TILE_ATOMS 8
#define TILE_ROWS  96                  // 8 atoms * 12 edges
#define NTILES     (NN / TILE_ATOMS)   // 12500
#define SLOTS      24                  // full-K slots per A row (fallback kernel)
#define WPK_L      (48 * 64 * 8)       // ushorts per layer of packed W
#define CONV_GRID  750                 // <= 768 resident at 3 blk/CU
#define ETILES     1563                // ceil(NN/64)
#define PCHUNK_ROWS 128
#define PCHUNK_F32  (PCHUNK_ROWS * NBR)        // 5248 f32 = 20992 B (16B aligned)
#define PCHUNK_U4   (PCHUNK_F32 / 4)           // 1312
#define NPCHUNK     ((NN * MM) / PCHUNK_ROWS)  // 9375
#define LOG2E_F    1.44269504088896341f
#define LN2_F      0.69314718055994531f

typedef __attribute__((ext_vector_type(8))) short bf16x8;
typedef __attribute__((ext_vector_type(4))) float f32x4;

__device__ __forceinline__ float softplusf(float v) {
    return fmaxf(v, 0.f) + log1pf(expf(-fabsf(v)));
}
__device__ __forceinline__ float sigmoidf_(float v) {
    return 1.f / (1.f + expf(-v));
}
__device__ __forceinline__ ushort f2bf(float f) {
    __hip_bfloat16 h = __float2bfloat16(f);
    return *(ushort*)&h;
}
__device__ __forceinline__ float bf2f(ushort h) {
    uint u = ((uint)h) << 16;
    return __uint_as_float(u);
}
// async global->LDS, 16B per lane; LDS dest = wave-uniform base + lane*16
__device__ __forceinline__ void gload_lds16(const void* gsrc, void* ldst) {
    __builtin_amdgcn_global_load_lds(
        (const __attribute__((address_space(1))) unsigned int*)gsrc,
        (__attribute__((address_space(3))) unsigned int*)ldst, 16, 0, 0);
}

// ---------------- packWemb ----------------
__global__ void packWemb_kernel(const float* __restrict__ embW, const float* __restrict__ mask,
                                ushort* __restrict__ wemb) {
    int b = blockIdx.x;            // 0..11 = cf*3 + kk
    int cf = b / 3;
    int kk = b - cf * 3;
    int lane = threadIdx.x;
    int c = cf * 16 + (lane & 15);
#pragma unroll
    for (int i = 0; i < 8; i++) {
        int k = kk * 32 + (lane >> 4) * 8 + i;
        float v = (k < ORIG) ? mask[k] * embW[k * FF + c] : 0.f;
        wemb[((size_t)b * 64 + lane) * 8 + i] = f2bf(v);
    }
}

// ---------------- embed_mfma ----------------
__launch_bounds__(256)
__global__ void embed_mfma(const float* __restrict__ af, const ushort* __restrict__ wemb,
                           const float* __restrict__ embb,
                           float* __restrict__ x, ushort* __restrict__ xb) {
    __shared__ __align__(16) ushort Ae[64 * 128];
    const int t = threadIdx.x;
    const int lane = t & 63;
    const int w = t >> 6;
    const int l15 = lane & 15;
    const int lg = lane >> 4;
    const int a0 = blockIdx.x * 64;

    bf16x8 bfrag[4][3];
#pragma unroll
    for (int cf = 0; cf < 4; cf++)
#pragma unroll
        for (int kk = 0; kk < 3; kk++)
            bfrag[cf][kk] = *(const bf16x8*)&wemb[(((size_t)(cf * 3 + kk)) * 64 + lane) * 8];

#pragma unroll
    for (int uu = 0; uu < 3; uu++) {
        int u = uu * 256 + t;
        int row = u / 12;
        int slot = u - row * 12;
        int a = a0 + row;
        if (a >= NN) a = NN - 1;
        const float* src = af + (size_t)a * ORIG + slot * 8;
        float v[8];
        float4 p0 = *(const float4*)src;
        v[0] = p0.x; v[1] = p0.y; v[2] = p0.z; v[3] = p0.w;
        if (slot < 11) {
            float4 p1 = *(const float4*)(src + 4);
            v[4] = p1.x; v[5] = p1.y; v[6] = p1.z; v[7] = p1.w;
        } else {
            v[4] = v[5] = v[6] = v[7] = 0.f;
        }
        uint4 val;
        val.x = (uint)f2bf(v[0]) | ((uint)f2bf(v[1]) << 16);
        val.y = (uint)f2bf(v[2]) | ((uint)f2bf(v[3]) << 16);
        val.z = (uint)f2bf(v[4]) | ((uint)f2bf(v[5]) << 16);
        val.w = (uint)f2bf(v[6]) | ((uint)f2bf(v[7]) << 16);
        *(uint4*)&Ae[row * 128 + ((slot ^ (row & 7)) * 8)] = val;
    }
    __syncthreads();

    f32x4 acc[4];
#pragma unroll
    for (int cf = 0; cf < 4; cf++) acc[cf] = (f32x4){0.f, 0.f, 0.f, 0.f};

#pragma unroll
    for (int kk = 0; kk < 3; kk++) {
        int row = w * 16 + l15;
        int slot = kk * 4 + lg;
        bf16x8 a = *(const bf16x8*)&Ae[row * 128 + ((slot ^ (row & 7)) * 8)];
#pragma unroll
        for (int cf = 0; cf < 4; cf++)
            acc[cf] = __builtin_amdgcn_mfma_f32_16x16x32_bf16(a, bfrag[cf][kk], acc[cf], 0, 0, 0);
    }

#pragma unroll
    for (int cf = 0; cf < 4; cf++) {
        int c = cf * 16 + l15;
        float bb = embb[c];
#pragma unroll
        for (int q = 0; q < 4; q++) {
            int a = a0 + w * 16 + lg * 4 + q;
            if (a < NN) {
                float v = acc[cf][q] + bb;
                x[(size_t)a * FF + c] = v;
                xb[(size_t)a * FF + c] = f2bf(v);
            }
        }
    }
}

// ---------------- packW ----------------
__global__ void packW_kernel(const float* __restrict__ fcW, ushort* __restrict__ wpk) {
    int b = blockIdx.x;            // 0..143 = l*48 + cf*6 + kk
    int l = b / 48;
    int r = b - l * 48;
    int cf = r / 6;
    int kk = r - cf * 6;
    int lane = threadIdx.x;
    int c = cf * 16 + (lane & 15);
#pragma unroll
    for (int i = 0; i < 8; i++) {
        int k = kk * 32 + (lane >> 4) * 8 + i;
        float v = (k < K2) ? fcW[(l * K2 + k) * GG + c] : 0.f;
        wpk[((size_t)b * 64 + lane) * 8 + i] = f2bf(v);
    }
}

// ---------------- prepack_nbr v2: LDS-staged coalesced conversion ----------------
__launch_bounds__(256)
__global__ void prepack_nbr(const float* __restrict__ nbr_fea, ushort* __restrict__ nbrb) {
    __shared__ float buf[PCHUNK_F32];   // 20.5 KB
    const int t = threadIdx.x;
    for (int chunk = blockIdx.x; chunk < NPCHUNK; chunk += gridDim.x) {
        const uint4* src = (const uint4*)(nbr_fea + (size_t)chunk * PCHUNK_F32);
        __syncthreads();   // protect buf from previous iteration readers
#pragma unroll
        for (int i = 0; i < 6; i++) {
            int u = i * 256 + t;
            if (u < PCHUNK_U4) *(uint4*)&buf[u * 4] = src[u];
        }
        __syncthreads();
#pragma unroll
        for (int i = 0; i < 4; i++) {   // 1024 out units = 4*256
            int u = i * 256 + t;
            int row = u >> 3;
            int kb = (u & 7) * 8;
            ushort h[8];
#pragma unroll
            for (int j = 0; j < 8; j++)
                h[j] = (kb + j < NBR) ? f2bf(buf[row * NBR + kb + j]) : (ushort)0;
            uint4 val;
            val.x = (uint)h[0] | ((uint)h[1] << 16);
            val.y = (uint)h[2] | ((uint)h[3] << 16);
            val.z = (uint)h[4] | ((uint)h[5] << 16);
            val.w = (uint)h[6] | ((uint)h[7] << 16);
            *(uint4*)&nbrb[((size_t)chunk * PCHUNK_ROWS + row) * 64 + kb] = val;
        }
    }
}

// ---------------- conv_fused: merged-phase triple-buffer, (256,3) ----------------
template <int MODE>
__launch_bounds__(256, 3)
__global__ void conv_fused(const ushort* __restrict__ xb, const ushort* __restrict__ nbrb,
                           const int* __restrict__ nidx, const ushort* __restrict__ wpk_l,
                           const float* __restrict__ fcb_l,
                           float* __restrict__ stats,
                           const float* __restrict__ sc1, const float* __restrict__ sh1,
                           float* __restrict__ summed, float* __restrict__ stats2) {
    __shared__ __align__(16) ushort As[3][TILE_ROWS * 64];   // 3 x 12.3 KB
    __shared__ int nbstage[2][TILE_ROWS];
    __shared__ float red[256];

    const int t = threadIdx.x;
    const int lane = t & 63;
    const int w = t >> 6;
    const int l15 = lane & 15;
    const int lg = lane >> 4;

    bf16x8 bfrag[2][6];
#pragma unroll
    for (int c2 = 0; c2 < 2; c2++)
#pragma unroll
        for (int kk = 0; kk < 6; kk++)
            bfrag[c2][kk] = *(const bf16x8*)&wpk_l[((((w + 4 * c2) * 6 + kk) * 64 + lane) * 8)];

    const int chF = w * 16 + l15;
    float scF = 0.f, shF = 0.f, scC = 0.f, shC = 0.f;
    if (MODE == 1) {
        scF = sc1[chF]; shF = sh1[chF];
        scC = sc1[chF + 64]; shC = sh1[chF + 64];
    }

    float sAF = 0.f, sBF = 0.f, sAC = 0.f, sBC = 0.f;
    float s2a = 0.f, s2b = 0.f;

    int pt = t; if (pt >= TILE_ROWS) pt -= TILE_ROWS; if (pt >= TILE_ROWS) pt -= TILE_ROWS;
    const int pidx = (pt & 7) * MM + (pt >> 3);

    int rowi[3], sli[3];
#pragma unroll
    for (int i = 0; i < 3; i++) {
        int u = w * 192 + i * 64 + lane;
        rowi[i] = u >> 3;
        sli[i] = (u & 7) ^ (rowi[i] & 7);
    }
    const ushort* p0p[3];
    const ushort* p2p[3];
#pragma unroll
    for (int i = 0; i < 3; i++) {
        p0p[i] = xb + ((size_t)blockIdx.x * TILE_ATOMS + (rowi[i] & 7)) * 64 + sli[i] * 8;
        p2p[i] = nbrb + ((size_t)blockIdx.x * TILE_ROWS + (rowi[i] & 7) * MM + (rowi[i] >> 3)) * 64
                 + sli[i] * 8;
    }
    const size_t st0 = (size_t)CONV_GRID * TILE_ATOMS * 64;
    const size_t st2 = (size_t)CONV_GRID * TILE_ROWS * 64;

    auto issue0 = [&]() {
#pragma unroll
        for (int i = 0; i < 3; i++) {
            gload_lds16(p0p[i], &As[0][(w * 192 + i * 64) * 8]);
            p0p[i] += st0;
        }
    };
    auto issue1 = [&](int nb) {
#pragma unroll
        for (int i = 0; i < 3; i++)
            gload_lds16(xb + (size_t)nbstage[nb][rowi[i]] * 64 + sli[i] * 8,
                        &As[1][(w * 192 + i * 64) * 8]);
    };
    auto issue2 = [&]() {
#pragma unroll
        for (int i = 0; i < 3; i++) {
            gload_lds16(p2p[i], &As[2][(w * 192 + i * 64) * 8]);
            p2p[i] += st2;
        }
    };

    int tile = blockIdx.x;   // grid 750, NTILES 12500: every block has >= 16 tiles
    int idx_cur;
    {   // prologue
        int nx0 = nidx[tile * TILE_ROWS + pidx];
        int nx1 = nidx[(tile + CONV_GRID) * TILE_ROWS + pidx];
        if (t < TILE_ROWS) { nbstage[0][t] = nx0; nbstage[1][t] = nx1; }
        __syncthreads();
        idx_cur = nidx[(tile + 2 * CONV_GRID) * TILE_ROWS + pidx];
        issue0(); issue1(0); issue2();
        asm volatile("" ::: "memory");
    }

    for (int it = 0; tile < NTILES; tile += CONV_GRID, ++it) {
        const bool have1 = (tile + CONV_GRID)     < NTILES;
        const bool have2 = (tile + 2 * CONV_GRID) < NTILES;
        const bool have3 = (tile + 3 * CONV_GRID) < NTILES;

        int idx_next = 0;
        if (have3) idx_next = nidx[(tile + 3 * CONV_GRID) * TILE_ROWS + pidx];

        f32x4 acc[6][2];
#pragma unroll
        for (int rf = 0; rf < 6; rf++)
#pragma unroll
            for (int c2 = 0; c2 < 2; c2++) acc[rf][c2] = (f32x4){0.f, 0.f, 0.f, 0.f};

        // ============ merged phase 0+1: consume As[0] (kk 0,1) + As[1] (kk 2,3) ============
        if (it == 0)       { asm volatile("s_waitcnt vmcnt(4)"  ::: "memory"); }
        else if (have3) {
            if (MODE == 1) { asm volatile("s_waitcnt vmcnt(8)"  ::: "memory"); }
            else           { asm volatile("s_waitcnt vmcnt(4)"  ::: "memory"); }
        } else {
            if (MODE == 1) { asm volatile("s_waitcnt vmcnt(7)"  ::: "memory"); }
            else           { asm volatile("s_waitcnt vmcnt(3)"  ::: "memory"); }
        }
        __builtin_amdgcn_s_barrier();
        __builtin_amdgcn_sched_barrier(0);
#pragma unroll
        for (int sb = 0; sb < 2; sb++) {
#pragma unroll
            for (int kx = 0; kx < 2; kx++) {
                int kk = sb * 2 + kx;
#pragma unroll
                for (int rf = 0; rf < 6; rf++) {
                    int row = rf * 16 + l15;
                    int s8r = kx * 4 + lg;
                    bf16x8 a = *(const bf16x8*)&As[sb][row * 64 + ((s8r ^ (row & 7)) * 8)];
                    acc[rf][0] = __builtin_amdgcn_mfma_f32_16x16x32_bf16(a, bfrag[0][kk], acc[rf][0], 0, 0, 0);
                    acc[rf][1] = __builtin_amdgcn_mfma_f32_16x16x32_bf16(a, bfrag[1][kk], acc[rf][1], 0, 0, 0);
                }
            }
        }
        asm volatile("" ::: "memory");
        __builtin_amdgcn_s_barrier();
        if (have1) { issue0(); issue1((it + 1) & 1); }
        asm volatile("" ::: "memory");

        // ============ phase 2: consume As[2] (kk 4,5) + epilogue ============
        if (it == 0)            { asm volatile("s_waitcnt vmcnt(7)" ::: "memory"); }
        else if (have1 && have3){ asm volatile("s_waitcnt vmcnt(7)" ::: "memory"); }
        else if (have1)         { asm volatile("s_waitcnt vmcnt(6)" ::: "memory"); }
        else                    { asm volatile("s_waitcnt vmcnt(0)" ::: "memory"); }
        __builtin_amdgcn_s_barrier();
        __builtin_amdgcn_sched_barrier(0);
#pragma unroll
        for (int kx = 0; kx < 2; kx++) {
            int kk = 4 + kx;
#pragma unroll
            for (int rf = 0; rf < 6; rf++) {
                int row = rf * 16 + l15;
                int s8r = kx * 4 + lg;
                bf16x8 a = *(const bf16x8*)&As[2][row * 64 + ((s8r ^ (row & 7)) * 8)];
                acc[rf][0] = __builtin_amdgcn_mfma_f32_16x16x32_bf16(a, bfrag[0][kk], acc[rf][0], 0, 0, 0);
                acc[rf][1] = __builtin_amdgcn_mfma_f32_16x16x32_bf16(a, bfrag[1][kk], acc[rf][1], 0, 0, 0);
            }
        }

        if (MODE == 0) {
#pragma unroll
            for (int rf = 0; rf < 6; rf++)
#pragma unroll
                for (int q = 0; q < 4; q++) {
                    float a0 = acc[rf][0][q];
                    float a1 = acc[rf][1][q];
                    sAF += a0; sBF = fmaf(a0, a0, sBF);
                    sAC += a1; sBC = fmaf(a1, a1, sBC);
                }
        } else {
            float psum[4] = {0.f, 0.f, 0.f, 0.f};
#pragma unroll
            for (int rf = 0; rf < 6; rf++)
#pragma unroll
                for (int q = 0; q < 4; q++) {
                    float gF = fmaf(acc[rf][0][q], scF, shF);   // log2 domain
                    float gC = fmaf(acc[rf][1][q], scC, shC);
                    float sig = __builtin_amdgcn_rcpf(1.f + __builtin_amdgcn_exp2f(-gF));
                    float sp  = fmaxf(gC, 0.f)
                              + __builtin_amdgcn_logf(1.f + __builtin_amdgcn_exp2f(-fabsf(gC)));
                    psum[q] = fmaf(sig, sp, psum[q]);
                }
#pragma unroll
            for (int q = 0; q < 4; q++) {
                psum[q] *= LN2_F;
                psum[q] += __shfl_xor(psum[q], 32, 64);
            }
            if (lg < 2) {
                int atom0 = tile * TILE_ATOMS;
#pragma unroll
                for (int q = 0; q < 4; q++) {
                    int a_loc = (lg & 1) * 4 + q;
                    float sm = psum[q];
                    summed[(size_t)(atom0 + a_loc) * FF + chF] = sm;
                    s2a += sm; s2b += sm * sm;
                }
            }
        }

        // nbstage <- idx_cur (loaded >=1 tile ago: implicit wait loose, no drain)
        if (have2 && t < TILE_ROWS) nbstage[it & 1][t] = idx_cur;
        idx_cur = idx_next;
        asm volatile("s_waitcnt lgkmcnt(0)" ::: "memory");
        __builtin_amdgcn_s_barrier();
        if (have1) issue2();
        asm volatile("" ::: "memory");
    }

    // ------- end-of-kernel stats reductions -------
    if (MODE == 0) {
        __syncthreads(); red[t] = sAF; __syncthreads();
        if (t < 64) {
            float s = 0.f;
#pragma unroll
            for (int g2 = 0; g2 < 4; g2++) s += red[(t >> 4) * 64 + g2 * 16 + (t & 15)];
            atomicAdd(&stats[t], s);
        }
        __syncthreads(); red[t] = sBF; __syncthreads();
        if (t < 64) {
            float s = 0.f;
#pragma unroll
            for (int g2 = 0; g2 < 4; g2++) s += red[(t >> 4) * 64 + g2 * 16 + (t & 15)];
            atomicAdd(&stats[128 + t], s);
        }
        __syncthreads(); red[t] = sAC; __syncthreads();
        if (t < 64) {
            float s = 0.f;
#pragma unroll
            for (int g2 = 0; g2 < 4; g2++) s += red[(t >> 4) * 64 + g2 * 16 + (t & 15)];
            atomicAdd(&stats[64 + t], s);
        }
        __syncthreads(); red[t] = sBC; __syncthreads();
        if (t < 64) {
            float s = 0.f;
#pragma unroll
            for (int g2 = 0; g2 < 4; g2++) s += red[(t >> 4) * 64 + g2 * 16 + (t & 15)];
            atomicAdd(&stats[192 + t], s);
        }
    } else {
        __syncthreads(); red[t] = s2a; __syncthreads();
        if (t < 64) {
            float s = 0.f;
#pragma unroll
            for (int g2 = 0; g2 < 4; g2++) s += red[(t >> 4) * 64 + g2 * 16 + (t & 15)];
            atomicAdd(&stats2[t], s);
        }
        __syncthreads(); red[t] = s2b; __syncthreads();
        if (t < 64) {
            float s = 0.f;
#pragma unroll
            for (int g2 = 0; g2 < 4; g2++) s += red[(t >> 4) * 64 + g2 * 16 + (t & 15)];
            atomicAdd(&stats2[64 + t], s);
        }
    }
}

// ---------------- legacy R4 two-pass conv (ws fallback; raw-acc stats, fold=0) ----------------
template <int PASS>
__launch_bounds__(256, 2)
__global__ void conv_mfma(const ushort* __restrict__ xb, const float* __restrict__ nbr_fea,
                          const int* __restrict__ nidx, const ushort* __restrict__ wpk_l,
                          const float* __restrict__ fcb_l,
                          float* __restrict__ stats,
                          const float* __restrict__ sc1, const float* __restrict__ sh1,
                          float* __restrict__ summed, float* __restrict__ stats2) {
    __shared__ __align__(16) ushort As[TILE_ROWS * 192];
    __shared__ int nb[TILE_ROWS];
    __shared__ float gacc[TILE_ATOMS * FF];
    __shared__ float red[256];

    const int t = threadIdx.x;
    const int lane = t & 63;
    const int w = t >> 6;
    const int l15 = lane & 15;
    const int lg = lane >> 4;

    bf16x8 bfrag[2][6];
#pragma unroll
    for (int c2 = 0; c2 < 2; c2++)
#pragma unroll
        for (int kk = 0; kk < 6; kk++)
            bfrag[c2][kk] = *(const bf16x8*)&wpk_l[((((w + 4 * c2) * 6 + kk) * 64 + lane) * 8)];

    const int chF = w * 16 + l15;
    const int chC = chF + 64;
    const float bF = fcb_l[chF], bC = fcb_l[chC];
    float scF = 0.f, shF = 0.f, scC = 0.f, shC = 0.f;
    if (PASS == 1) { scF = sc1[chF]; shF = sh1[chF]; scC = sc1[chC]; shC = sh1[chC]; }

    float sAF = 0.f, sBF = 0.f, sAC = 0.f, sBC = 0.f;
    float s2a = 0.f, s2b = 0.f;

    for (int tile = blockIdx.x; tile < NTILES; tile += gridDim.x) {
        const int ebase = tile * TILE_ROWS;
        __syncthreads();
        if (t < TILE_ROWS) nb[t] = nidx[ebase + t];
        if (PASS == 1) { gacc[t] = 0.f; gacc[256 + t] = 0.f; }
        __syncthreads();

#pragma unroll
        for (int e = t; e < TILE_ROWS * SLOTS; e += 256) {
            int row = e / SLOTS;
            int slot = e - row * SLOTS;
            uint4 val;
            if (slot < 16) {
                int a = (slot < 8) ? (tile * TILE_ATOMS + row / 12) : nb[row];
                val = *(const uint4*)&xb[a * 64 + (slot & 7) * 8];
            } else {
                int kb = (slot - 16) * 8;
                const float* src = nbr_fea + (size_t)(ebase + row) * NBR + kb;
                ushort h[8];
#pragma unroll
                for (int i = 0; i < 8; i++)
                    h[i] = (kb + i < NBR) ? f2bf(src[i]) : (ushort)0;
                val.x = (uint)h[0] | ((uint)h[1] << 16);
                val.y = (uint)h[2] | ((uint)h[3] << 16);
                val.z = (uint)h[4] | ((uint)h[5] << 16);
                val.w = (uint)h[6] | ((uint)h[7] << 16);
            }
            *(uint4*)&As[row * 192 + ((slot ^ (row & 7)) * 8)] = val;
        }
        __syncthreads();

        f32x4 acc[6][2];
#pragma unroll
        for (int rf = 0; rf < 6; rf++)
#pragma unroll
            for (int c2 = 0; c2 < 2; c2++) acc[rf][c2] = (f32x4){0.f, 0.f, 0.f, 0.f};

#pragma unroll
        for (int kk = 0; kk < 6; kk++) {
#pragma unroll
            for (int rf = 0; rf < 6; rf++) {
                int row = rf * 16 + l15;
                int slot = kk * 4 + lg;
                bf16x8 a = *(const bf16x8*)&As[row * 192 + ((slot ^ (row & 7)) * 8)];
                acc[rf][0] = __builtin_amdgcn_mfma_f32_16x16x32_bf16(a, bfrag[0][kk], acc[rf][0], 0, 0, 0);
                acc[rf][1] = __builtin_amdgcn_mfma_f32_16x16x32_bf16(a, bfrag[1][kk], acc[rf][1], 0, 0, 0);
            }
        }

        if (PASS == 0) {
#pragma unroll
            for (int rf = 0; rf < 6; rf++)
#pragma unroll
                for (int q = 0; q < 4; q++) {
                    float a0 = acc[rf][0][q];
                    float a1 = acc[rf][1][q];
                    sAF += a0; sBF = fmaf(a0, a0, sBF);
                    sAC += a1; sBC = fmaf(a1, a1, sBC);
                }
        } else {
#pragma unroll
            for (int rf = 0; rf < 6; rf++) {
                int r0 = rf * 16 + lg * 4;
                float p = 0.f;
#pragma unroll
                for (int q = 0; q < 4; q++) {
                    float gF = (acc[rf][0][q] + bF) * scF + shF;
                    float gC = (acc[rf][1][q] + bC) * scC + shC;
                    p += sigmoidf_(gF) * softplusf(gC);
                }
                atomicAdd(&gacc[(r0 / 12) * FF + chF], p);
            }
            __syncthreads();
#pragma unroll
            for (int rep = 0; rep < 2; rep++) {
                int idx = rep * 256 + t;
                int a = idx >> 6, c = idx & 63;
                float sm = gacc[idx];
                summed[(tile * TILE_ATOMS + a) * FF + c] = sm;
                s2a += sm; s2b += sm * sm;
            }
        }
    }

    if (PASS == 0) {
        __syncthreads(); red[t] = sAF; __syncthreads();
        if (t < 64) {
            float s = 0.f;
#pragma unroll
            for (int g2 = 0; g2 < 4; g2++) s += red[(t >> 4) * 64 + g2 * 16 + (t & 15)];
            atomicAdd(&stats[t], s);
        }
        __syncthreads(); red[t] = sBF; __syncthreads();
        if (t < 64) {
            float s = 0.f;
#pragma unroll
            for (int g2 = 0; g2 < 4; g2++) s += red[(t >> 4) * 64 + g2 * 16 + (t & 15)];
            atomicAdd(&stats[128 + t], s);
        }
        __syncthreads(); red[t] = sAC; __syncthreads();
        if (t < 64) {
            float s = 0.f;
#pragma unroll
            for (int g2 = 0; g2 < 4; g2++) s += red[(t >> 4) * 64 + g2 * 16 + (t & 15)];
            atomicAdd(&stats[64 + t], s);
        }
        __syncthreads(); red[t] = sBC; __syncthreads();
        if (t < 64) {
            float s = 0.f;
#pragma unroll
            for (int g2 = 0; g2 < 4; g2++) s += red[(t >> 4) * 64 + g2 * 16 + (t & 15)];
            atomicAdd(&stats[192 + t], s);
        }
    } else {
        __syncthreads(); red[t] = s2a; __syncthreads();
        if (t < 64) {
            float s = red[t] + red[64 + t] + red[128 + t] + red[192 + t];
            atomicAdd(&stats2[t], s);
        }
        __syncthreads(); red[t] = s2b; __syncthreads();
        if (t < 64) {
            float s = red[t] + red[64 + t] + red[128 + t] + red[192 + t];
            atomicAdd(&stats2[64 + t], s);
        }
    }
}

// ---------------- bn finalize ----------------
__global__ void fin1_kernel(const float* __restrict__ stats, const float* __restrict__ fcb_l,
                            const float* __restrict__ g, const float* __restrict__ b,
                            float* __restrict__ sc, float* __restrict__ sh, int fold) {
    int c = threadIdx.x;  // 128
    const float inv = 1.f / (float)(NN * MM);
    float bia = fcb_l[c];
    float Sa = stats[c], Sb = stats[128 + c];
    float mu = Sa * inv + bia;
    float ex2 = (Sb + 2.f * bia * Sa) * inv + bia * bia;
    float var = ex2 - mu * mu;
    float s = rsqrtf(var + EPSV) * g[c];
    float scv = s;
    float shv = b[c] - mu * s;
    if (fold) { scv *= LOG2E_F; shv *= LOG2E_F; }
    sc[c] = scv;
    sh[c] = shv;
}

__global__ void fin2_kernel(const float* __restrict__ stats2, const float* __restrict__ g,
                            const float* __restrict__ b, float* __restrict__ sc, float* __restrict__ sh) {
    int c = threadIdx.x;  // 64
    const float inv = 1.f / (float)NN;
    float mu = stats2[c] * inv;
    float var = stats2[64 + c] * inv - mu * mu;
    float s = rsqrtf(var + EPSV) * g[c];
    sc[c] = s;
    sh[c] = b[c] - mu * s;
}

// ---------------- x = softplus(x + bn2(summed)) ; refresh xb ----------------
__global__ void update_x_kernel(float* __restrict__ x, ushort* __restrict__ xb,
                                const float* __restrict__ summed,
                                const float* __restrict__ sc2, const float* __restrict__ sh2) {
    for (int idx = blockIdx.x * blockDim.x + threadIdx.x; idx < NN * FF;
         idx += gridDim.x * blockDim.x) {
        int c = idx & 63;
        float v = softplusf(x[idx] + summed[idx] * sc2[c] + sh2[c]);
        x[idx] = v;
        xb[idx] = f2bf(v);
    }
}

// ---------------- last layer: update_x fused with segment pooling ----------------
__global__ void update_x_pool_kernel(const float* __restrict__ x,
                                     const float* __restrict__ summed,
                                     const float* __restrict__ sc2, const float* __restrict__ sh2,
                                     const int* __restrict__ seg,
                                     float* __restrict__ csum, float* __restrict__ ccnt) {
    for (int idx = blockIdx.x * blockDim.x + threadIdx.x; idx < NN * FF;
         idx += gridDim.x * blockDim.x) {
        int i = idx >> 6;
        int c = idx & 63;
        float v = softplusf(x[idx] + summed[idx] * sc2[c] + sh2[c]);
        atomicAdd(&csum[seg[i] * FF + c], v);
        if (c == 0) atomicAdd(&ccnt[seg[i]], 1.f);
    }
}

// ---------------- per-crystal head ----------------
__global__ void head_kernel(const float* __restrict__ csum, const float* __restrict__ ccnt,
                            const float* __restrict__ c2fW, const float* __restrict__ c2fb,
                            const float* __restrict__ outW, const float* __restrict__ outb,
                            float* __restrict__ out) {
    __shared__ float pl[FF];
    __shared__ float red[HH];
    int c = blockIdx.x;
    int t = threadIdx.x;
    if (t < FF) {
        float cnt = fmaxf(ccnt[c], 1.f);
        pl[t] = softplusf(csum[c * FF + t] / cnt);
    }
    __syncthreads();
    float acc = c2fb[t];
    for (int f = 0; f < FF; f++) acc += pl[f] * c2fW[f * HH + t];
    red[t] = softplusf(acc) * outW[t];
    __syncthreads();
    for (int s = 64; s > 0; s >>= 1) {
        if (t < s) red[t] += red[t + s];
        __syncthreads();
    }
    if (t == 0) out[c] = red[0] + outb[0];
}

extern "C" void kernel_launch(void* const* d_in, const int* in_sizes, int n_in,
                              void* d_out, int out_size, void* d_ws, size_t ws_size,
                              hipStream_t stream) {
    const float* atom_fea = (const float*)d_in[0];
    const float* nbr_fea  = (const float*)d_in[1];
    const int*   nbr_idx  = (const int*)d_in[2];
    const int*   seg      = (const int*)d_in[3];
    const float* mask = (const float*)d_in[5];
    const float* embW = (const float*)d_in[6];
    const float* embb = (const float*)d_in[7];
    const float* fcW  = (const float*)d_in[8];
    const float* fcb  = (const float*)d_in[9];
    const float* bn1g = (const float*)d_in[10];
    const float* bn1b = (const float*)d_in[11];
    const float* bn2g = (const float*)d_in[12];
    const float* bn2b = (const float*)d_in[13];
    const float* c2fW = (const float*)d_in[14];
    const float* c2fb = (const float*)d_in[15];
    const float* outW = (const float*)d_in[16];
    const float* outb = (const float*)d_in[17];
    float* out = (float*)d_out;

    // ws layout (f32 region, then ushort region; ccnt adjacent to csum!)
    float* ws     = (float*)d_ws;
    float* x      = ws;                       // N*F
    float* summed = x + NN * FF;              // N*F
    float* csum   = summed + NN * FF;         // CC*FF
    float* ccnt   = csum + CC * FF;           // CC (+3 pad -> 3128)
    float* stats  = ccnt + 3128;              // 256
    float* stats2 = stats + 256;              // 128
    float* sc1    = stats2 + 128;             // 128
    float* sh1    = sc1 + 128;                // 128
    float* sc2    = sh1 + 128;                // 64
    float* sh2    = sc2 + 64;                 // 64
    ushort* xb    = (ushort*)(sh2 + 64);      // N*F bf16
    ushort* wpk   = xb + NN * FF;             // 3 * WPK_L
    ushort* wemb  = wpk + 3 * WPK_L;          // 6144 (pad 8192)
    ushort* nbrb  = wemb + 8192;              // N*M*64 bf16

    const size_t need_full =
        (size_t)((char*)(nbrb + (size_t)NN * MM * 64) - (char*)d_ws);
    const bool full = (ws_size >= need_full);

    packW_kernel<<<144, 64, 0, stream>>>(fcW, wpk);
    packWemb_kernel<<<12, 64, 0, stream>>>(embW, mask, wemb);
    embed_mfma<<<ETILES, 256, 0, stream>>>(atom_fea, wemb, embb, x, xb);
    if (full) prepack_nbr<<<2048, 256, 0, stream>>>(nbr_fea, nbrb);
    hipMemsetAsync(csum, 0, (CC * FF + CC) * sizeof(float), stream);

    for (int l = 0; l < NCONV; l++) {
        const ushort* wpk_l = wpk + l * WPK_L;
        hipMemsetAsync(stats, 0, (256 + 128) * sizeof(float), stream);
        if (full) {
            conv_fused<0><<<CONV_GRID, 256, 0, stream>>>(xb, nbrb, nbr_idx, wpk_l,
                                                         fcb + l * GG, stats,
                                                         nullptr, nullptr, nullptr, nullptr);
            fin1_kernel<<<1, 128, 0, stream>>>(stats, fcb + l * GG,
                                               bn1g + l * GG, bn1b + l * GG, sc1, sh1, 1);
            conv_fused<1><<<CONV_GRID, 256, 0, stream>>>(xb, nbrb, nbr_idx, wpk_l,
                                                         fcb + l * GG, nullptr,
                                                         sc1, sh1, summed, stats2);
        } else {
            conv_mfma<0><<<2048, 256, 0, stream>>>(xb, nbr_fea, nbr_idx, wpk_l, fcb + l * GG,
                                                   stats, nullptr, nullptr, nullptr, nullptr);
            fin1_kernel<<<1, 128, 0, stream>>>(stats, fcb + l * GG,
                                               bn1g + l * GG, bn1b + l * GG, sc1, sh1, 0);
            conv_mfma<1><<<2048, 256, 0, stream>>>(xb, nbr_fea, nbr_idx, wpk_l, fcb + l * GG,
                                                   nullptr, sc1, sh1, summed, stats2);
        }
        fin2_kernel<<<1, 64, 0, stream>>>(stats2, bn2g + l * FF, bn2b + l * FF, sc2, sh2);
        if (l < NCONV - 1) {
            update_x_kernel<<<2048, 256, 0, stream>>>(x, xb, summed, sc2, sh2);
        } else {
            update_x_pool_kernel<<<2048, 256, 0, stream>>>(x, summed, sc2, sh2,
                                                           seg, csum, ccnt);
        }
    }

    head_kernel<<<CC, 128, 0, stream>>>(csum, ccnt, c2fW, c2fb, outW, outb, out);
}